// Round 1
// baseline (2081.003 us; speedup 1.0000x reference)
//
#include <hip/hip_runtime.h>
#include <cmath>

#define E_INC   393216
#define NN_     12288
#define MM_     16384
#define FDIM    256
#define CDIM    128

#define BM 64
#define BN 64
#define BK 16

__host__ __device__ inline int cntBase(int r){ return r<3 ? r*NN_ : 3*NN_ + (r-3)*MM_; }
__host__ __device__ inline int stBase(int r){ return r<3 ? r*(NN_+1) : 3*(NN_+1) + (r-3)*(MM_+1); }

__device__ __forceinline__ float lrelu(float v){ return v >= 0.0f ? v : 0.2f*v; }

struct Ptrs6 { const int* p[6]; };

// ---------------- CSR build ----------------
__global__ __launch_bounds__(256) void hist_kernel(Ptrs6 ip, int* __restrict__ cnt){
  int r = blockIdx.y;
  int e = blockIdx.x*256 + threadIdx.x;
  atomicAdd(&cnt[cntBase(r) + ip.p[r][e]], 1);
}

__global__ __launch_bounds__(1024) void scan_kernel(const int* __restrict__ cnt,
                                                    int* __restrict__ starts,
                                                    int* __restrict__ cur){
  int r = blockIdx.x;
  int nb = (r<3) ? NN_ : MM_;
  int cb = cntBase(r), sb = stBase(r);
  int t = threadIdx.x;
  int chunk = nb >> 10;               // 12 or 16
  int o = t*chunk;
  int s = 0;
  for (int j=0;j<chunk;++j) s += cnt[cb+o+j];
  __shared__ int sd[1024];
  sd[t] = s; __syncthreads();
  for (int ofs=1; ofs<1024; ofs<<=1){
    int v = (t>=ofs) ? sd[t-ofs] : 0;
    __syncthreads();
    sd[t] += v; __syncthreads();
  }
  int run = sd[t] - s;
  for (int j=0;j<chunk;++j){
    int c = cnt[cb+o+j];
    starts[sb+o+j] = run; cur[cb+o+j] = run;
    run += c;
  }
  if (t == 1023) starts[sb+nb] = run;
}

__global__ __launch_bounds__(256) void fill_kernel(Ptrs6 ip, int* __restrict__ cur,
                                                   int* __restrict__ lists){
  int r = blockIdx.y;
  int e = blockIdx.x*256 + threadIdx.x;
  int key = ip.p[r][e];
  int pos = atomicAdd(&cur[cntBase(r)+key], 1);
  lists[(size_t)r*E_INC + pos] = e;
}

// sort each bucket ascending -> accumulation order == numpy sequential order
__global__ __launch_bounds__(256) void sortb_kernel(const int* __restrict__ starts,
                                                    int* __restrict__ lists){
  int r = blockIdx.y;
  int nb = (r<3) ? NN_ : MM_;
  int b = blockIdx.x*256 + threadIdx.x;
  if (b >= nb) return;
  int sb = stBase(r);
  int lo = starts[sb+b], hi = starts[sb+b+1];
  int* lst = lists + (size_t)r*E_INC;
  for (int i=lo+1; i<hi; ++i){
    int key = lst[i]; int j = i-1;
    while (j>=lo && lst[j]>key){ lst[j+1]=lst[j]; --j; }
    lst[j+1]=key;
  }
}

// ---------------- fp32 GEMMs ----------------
#define FMA4(i, a) \
  acc[i][0]=fmaf(a,bv.x,acc[i][0]); acc[i][1]=fmaf(a,bv.y,acc[i][1]); \
  acc[i][2]=fmaf(a,bv.z,acc[i][2]); acc[i][3]=fmaf(a,bv.w,acc[i][3]);

// C[rows x N] = A[rows x 256] @ W[seg][256 x N] (+bias) (opt leaky); ldc = N
__global__ __launch_bounds__(256)
void gemm_nn(const float* __restrict__ A, const float* __restrict__ W,
             const float* __restrict__ bias, float* __restrict__ C,
             int N, int segShift, int act)
{
  __shared__ alignas(16) float As[BK][BM+4];
  __shared__ alignas(16) float Bs[BK][BN+4];
  int t = threadIdx.x;
  int bm = blockIdx.x * BM;
  int bn = blockIdx.y * BN;
  int seg = bm >> segShift;
  const float* Wp = W + (size_t)seg * FDIM * N;
  int tx = t & 15, ty = t >> 4;
  int arow = t >> 2, akq = (t & 3) << 2;
  int brow = t >> 4, bcg = (t & 15) << 2;

  float acc[4][4] = {};
  for (int k0 = 0; k0 < FDIM; k0 += BK){
    float4 a4 = *(const float4*)(A + (size_t)(bm+arow)*FDIM + k0 + akq);
    As[akq+0][arow]=a4.x; As[akq+1][arow]=a4.y; As[akq+2][arow]=a4.z; As[akq+3][arow]=a4.w;
    float4 b4 = *(const float4*)(Wp + (size_t)(k0+brow)*N + bn + bcg);
    *(float4*)&Bs[brow][bcg] = b4;
    __syncthreads();
#pragma unroll
    for (int kk=0; kk<BK; ++kk){
      float4 av = *(const float4*)&As[kk][ty<<2];
      float4 bv = *(const float4*)&Bs[kk][tx<<2];
      FMA4(0, av.x) FMA4(1, av.y) FMA4(2, av.z) FMA4(3, av.w)
    }
    __syncthreads();
  }
  int c0 = bn + (tx<<2);
  float4 bb = make_float4(0.f,0.f,0.f,0.f);
  if (bias) bb = *(const float4*)(bias + (size_t)seg*N + c0);
#pragma unroll
  for (int i=0;i<4;++i){
    float4 o = make_float4(acc[i][0],acc[i][1],acc[i][2],acc[i][3]);
    if (bias){ o.x+=bb.x; o.y+=bb.y; o.z+=bb.z; o.w+=bb.w; }
    if (act){ o.x=lrelu(o.x); o.y=lrelu(o.y); o.z=lrelu(o.z); o.w=lrelu(o.w); }
    *(float4*)(C + (size_t)(bm+(ty<<2)+i)*N + c0) = o;
  }
}

// C[4096 x 4096] (+colOff into ldc-row) = A[4096 x 128] @ B[4096 x 128]^T
__global__ __launch_bounds__(256)
void gemm_nt(const float* __restrict__ A, const float* __restrict__ B,
             float* __restrict__ C, int ldc, int colOff)
{
  __shared__ alignas(16) float As[BK][BM+4];
  __shared__ alignas(16) float Bs[BK][BN+4];
  int t = threadIdx.x;
  int bm = blockIdx.x * BM;
  int bn = blockIdx.y * BN;
  int tx = t & 15, ty = t >> 4;
  int arow = t >> 2, akq = (t & 3) << 2;

  float acc[4][4] = {};
  for (int k0 = 0; k0 < CDIM; k0 += BK){
    float4 a4 = *(const float4*)(A + (size_t)(bm+arow)*CDIM + k0 + akq);
    As[akq+0][arow]=a4.x; As[akq+1][arow]=a4.y; As[akq+2][arow]=a4.z; As[akq+3][arow]=a4.w;
    float4 b4 = *(const float4*)(B + (size_t)(bn+arow)*CDIM + k0 + akq);
    Bs[akq+0][arow]=b4.x; Bs[akq+1][arow]=b4.y; Bs[akq+2][arow]=b4.z; Bs[akq+3][arow]=b4.w;
    __syncthreads();
#pragma unroll
    for (int kk=0; kk<BK; ++kk){
      float4 av = *(const float4*)&As[kk][ty<<2];
      float4 bv = *(const float4*)&Bs[kk][tx<<2];
      FMA4(0, av.x) FMA4(1, av.y) FMA4(2, av.z) FMA4(3, av.w)
    }
    __syncthreads();
  }
#pragma unroll
  for (int i=0;i<4;++i){
    float4 o = make_float4(acc[i][0],acc[i][1],acc[i][2],acc[i][3]);
    *(float4*)(C + (size_t)(bm+(ty<<2)+i)*ldc + colOff + bn + (tx<<2)) = o;
  }
}

// ---------------- attention scalar pipeline ----------------
// out[w] = dot(Mx[w,:256], vec)   (fp64 accumulate, one wave per row)
__global__ __launch_bounds__(256)
void rowdot(const float* __restrict__ Mx, const float* __restrict__ vec,
            float* __restrict__ out, int rows)
{
  int g = blockIdx.x*256 + threadIdx.x;
  int w = g >> 6, lane = g & 63;
  if (w >= rows) return;
  const float* r = Mx + (size_t)w*FDIM;
  double s = 0.0;
#pragma unroll
  for (int c=lane; c<FDIM; c+=64) s = fma((double)r[c], (double)vec[c], s);
  for (int ofs=32; ofs; ofs>>=1) s += __shfl_down(s, ofs);
  if (lane==0) out[w] = (float)s;
}

__global__ __launch_bounds__(256)
void node_stats(const int* __restrict__ starts, const int* __restrict__ list,
                const int* __restrict__ ei, const float* __restrict__ s1,
                const float* __restrict__ s2, const float* __restrict__ hw,
                float* __restrict__ amax, float* __restrict__ asum,
                float* __restrict__ dinv)
{
  int g = blockIdx.x*256 + threadIdx.x;
  int w = g >> 6, lane = g & 63;
  if (w >= NN_) return;
  int lo = starts[w], hi = starts[w+1];
  float s1n = s1[w];
  float mx = -INFINITY;
  for (int i=lo+lane; i<hi; i+=64){
    int e = list[i];
    mx = fmaxf(mx, lrelu(s1n + s2[ei[e]]));
  }
  for (int ofs=32; ofs; ofs>>=1) mx = fmaxf(mx, __shfl_xor(mx, ofs));
  if (lo == hi) mx = 0.0f;            // isfinite(amax) -> 0 for empty segments
  double se = 0.0, sd = 0.0;
  for (int i=lo+lane; i<hi; i+=64){
    int e = list[i]; int m = ei[e];
    float a = lrelu(s1n + s2[m]);
    se += (double)expf(a - mx);
    sd += (double)hw[m];
  }
  for (int ofs=32; ofs; ofs>>=1){ se += __shfl_xor(se, ofs); sd += __shfl_xor(sd, ofs); }
  if (lane==0){
    amax[w] = mx;
    asum[w] = (float)se;
    float D = (float)sd;
    dinv[w] = (D > 0.0f) ? 1.0f/D : 0.0f;
  }
}

__global__ __launch_bounds__(256)
void alpha_kernel(const int* __restrict__ ni, const int* __restrict__ ei,
                  const float* __restrict__ s1, const float* __restrict__ s2,
                  const float* __restrict__ amax, const float* __restrict__ asum,
                  float* __restrict__ alpha)
{
  int e = blockIdx.x*256 + threadIdx.x;
  int n = ni[e];
  float a = lrelu(s1[n] + s2[ei[e]]);
  alpha[e] = expf(a - amax[n]) / asum[n];
}

// ---------------- propagation (gather via CSR, np-order exact) ----------------
__global__ __launch_bounds__(256)
void m_kernel(const int* __restrict__ estarts, const int* __restrict__ elist,
              const int* __restrict__ ni, const float* __restrict__ alpha,
              const float* __restrict__ xl, float* __restrict__ m)
{
  int g = blockIdx.x*256 + threadIdx.x;
  int w = g >> 6, lane = g & 63;
  if (w >= MM_) return;
  int lo = estarts[w], hi = estarts[w+1];
  float binv = (hi > lo) ? 1.0f/(float)(hi-lo) : 0.0f;
  float ax=0.f, ay=0.f, az=0.f, aw=0.f;
  int col = lane << 2;
  for (int i=lo; i<hi; ++i){
    int e = elist[i];
    float c = __fmul_rn(binv, alpha[e]);
    const float4 x4 = *(const float4*)(xl + (size_t)ni[e]*FDIM + col);
    ax = __fadd_rn(ax, __fmul_rn(c, x4.x));
    ay = __fadd_rn(ay, __fmul_rn(c, x4.y));
    az = __fadd_rn(az, __fmul_rn(c, x4.z));
    aw = __fadd_rn(aw, __fmul_rn(c, x4.w));
  }
  *(float4*)(m + (size_t)w*FDIM + col) = make_float4(ax,ay,az,aw);
}

__global__ __launch_bounds__(256)
void out_kernel(const int* __restrict__ nstarts, const int* __restrict__ nlist,
                const int* __restrict__ ei, const float* __restrict__ alpha,
                const float* __restrict__ dinv, const float* __restrict__ m,
                const float* __restrict__ bias, float* __restrict__ accb,
                int first, int finalAct)
{
  int g = blockIdx.x*256 + threadIdx.x;
  int w = g >> 6, lane = g & 63;
  if (w >= NN_) return;
  int lo = nstarts[w], hi = nstarts[w+1];
  float dv = dinv[w];
  float ax=0.f, ay=0.f, az=0.f, aw=0.f;
  int col = lane << 2;
  for (int i=lo; i<hi; ++i){
    int e = nlist[i];
    float c = __fmul_rn(dv, alpha[e]);
    const float4 m4 = *(const float4*)(m + (size_t)ei[e]*FDIM + col);
    ax = __fadd_rn(ax, __fmul_rn(c, m4.x));
    ay = __fadd_rn(ay, __fmul_rn(c, m4.y));
    az = __fadd_rn(az, __fmul_rn(c, m4.z));
    aw = __fadd_rn(aw, __fmul_rn(c, m4.w));
  }
  const float4 b4 = *(const float4*)(bias + col);
  ax = __fadd_rn(ax, b4.x); ay = __fadd_rn(ay, b4.y);
  az = __fadd_rn(az, b4.z); aw = __fadd_rn(aw, b4.w);
  float* p = accb + (size_t)w*FDIM + col;
  if (!first){
    float4 pr = *(const float4*)p;
    ax = __fadd_rn(pr.x, ax); ay = __fadd_rn(pr.y, ay);
    az = __fadd_rn(pr.z, az); aw = __fadd_rn(pr.w, aw);
  }
  if (finalAct){ ax=lrelu(ax); ay=lrelu(ay); az=lrelu(az); aw=lrelu(aw); }
  *(float4*)p = make_float4(ax,ay,az,aw);
}

// ---------------- host orchestration ----------------
extern "C" void kernel_launch(void* const* d_in, const int* in_sizes, int n_in,
                              void* d_out, int out_size, void* d_ws, size_t ws_size,
                              hipStream_t stream)
{
  (void)in_sizes; (void)n_in; (void)out_size; (void)ws_size;
  const float* g     = (const float*)d_in[0];
  const float* x     = (const float*)d_in[1];
  const float* hw    = (const float*)d_in[2];
  const float* hattr = (const float*)d_in[3];
  const int* ni[3]   = {(const int*)d_in[4], (const int*)d_in[6], (const int*)d_in[8]};
  const int* ei[3]   = {(const int*)d_in[5], (const int*)d_in[7], (const int*)d_in[9]};
  const float* W0  = (const float*)d_in[10];
  const float* b0  = (const float*)d_in[11];
  const float* Wh1 = (const float*)d_in[12];
  const float* att1= (const float*)d_in[13];
  const float* bc1 = (const float*)d_in[14];
  const float* W1  = (const float*)d_in[15];
  const float* b1  = (const float*)d_in[16];
  const float* Wh2 = (const float*)d_in[17];
  const float* att2= (const float*)d_in[18];
  const float* bc2 = (const float*)d_in[19];
  const float* Wg  = (const float*)d_in[20];
  const float* bg  = (const float*)d_in[21];
  const float* Wx  = (const float*)d_in[22];
  const float* bx  = (const float*)d_in[23];
  float* outp = (float*)d_out;

  // workspace layout (256B-aligned slabs)
  char* base = (char*)d_ws;
  size_t off = 0;
  auto alloc = [&](size_t bytes)->void*{
    void* p = base + off;
    off = (off + bytes + 255) & ~(size_t)255;
    return p;
  };
  const size_t SZ_H = (size_t)NN_*FDIM;
  float* hA    = (float*)alloc(SZ_H*4);
  float* xl    = (float*)alloc(SZ_H*4);
  float* acc   = (float*)alloc(SZ_H*4);
  float* mbuf  = (float*)alloc((size_t)MM_*FDIM*4);
  float* alphab= (float*)alloc((size_t)E_INC*4);
  float* s1    = (float*)alloc(NN_*4);
  float* s2    = (float*)alloc(MM_*4);
  float* vv    = (float*)alloc(FDIM*4);
  float* amax  = (float*)alloc(NN_*4);
  float* asum  = (float*)alloc(NN_*4);
  float* dinvb = (float*)alloc(NN_*4);
  float* ng1   = (float*)alloc((size_t)4096*CDIM*4);
  float* ng2   = (float*)alloc((size_t)4096*CDIM*4);
  float* xs1   = (float*)alloc((size_t)4096*CDIM*4);
  float* xs2   = (float*)alloc((size_t)4096*CDIM*4);
  int*   cnt   = (int*)alloc((size_t)(3*NN_+3*MM_)*4);
  int*   cur   = (int*)alloc((size_t)(3*NN_+3*MM_)*4);
  int*   stb   = (int*)alloc((size_t)(3*(NN_+1)+3*(MM_+1))*4);
  int*   lists = (int*)alloc((size_t)6*E_INC*4);

  // ---- CSR build (shared by both hyper layers) ----
  hipMemsetAsync(cnt, 0, (size_t)(3*NN_+3*MM_)*4, stream);
  Ptrs6 ip{{ni[0],ni[1],ni[2],ei[0],ei[1],ei[2]}};
  hist_kernel <<<dim3(E_INC/256,6),256,0,stream>>>(ip, cnt);
  scan_kernel <<<6,1024,0,stream>>>(cnt, stb, cur);
  fill_kernel <<<dim3(E_INC/256,6),256,0,stream>>>(ip, cur, lists);
  sortb_kernel<<<dim3(64,6),256,0,stream>>>(stb, lists);

  // ---- layer0: h = leaky(g @ W0[seg] + b0[seg]) ----
  gemm_nn<<<dim3(192,4),256,0,stream>>>(g, W0, b0, hA, FDIM, 12, 1);

  auto hyper = [&](const float* hin, const float* Whs, const float* atts, const float* bcs){
    for (int k=0;k<3;++k){
      const float* Wk   = Whs + (size_t)k*FDIM*FDIM;
      const float* attA = atts + (size_t)k*2*FDIM;
      const float* attB = attA + FDIM;
      const int* nst = stb + stBase(k);
      const int* nls = lists + (size_t)k*E_INC;
      const int* est = stb + stBase(3+k);
      const int* els = lists + (size_t)(3+k)*E_INC;
      gemm_nn    <<<dim3(192,4),256,0,stream>>>(hin, Wk, nullptr, xl, FDIM, 30, 0);
      rowdot     <<<64,  256,0,stream>>>(Wk, attB, vv, FDIM);          // v = W @ attB
      rowdot     <<<3072,256,0,stream>>>(xl, attA, s1, NN_);
      rowdot     <<<4096,256,0,stream>>>(hattr, vv, s2, MM_);
      node_stats <<<3072,256,0,stream>>>(nst, nls, ei[k], s1, s2, hw, amax, asum, dinvb);
      alpha_kernel<<<E_INC/256,256,0,stream>>>(ni[k], ei[k], s1, s2, amax, asum, alphab);
      m_kernel   <<<4096,256,0,stream>>>(est, els, ni[k], alphab, xl, mbuf);
      out_kernel <<<3072,256,0,stream>>>(nst, nls, ei[k], alphab, dinvb, mbuf,
                                         bcs + (size_t)k*FDIM, acc, k==0, k==2);
    }
  };

  // ---- hyper1 (reads hA, result -> acc, leaky fused on last branch) ----
  hyper(hA, Wh1, att1, bc1);
  // ---- layer1: hA = leaky(acc @ W1[seg] + b1[seg]) ----
  gemm_nn<<<dim3(192,4),256,0,stream>>>(acc, W1, b1, hA, FDIM, 12, 1);
  // ---- hyper2 (reads hA, result -> acc = final h) ----
  hyper(hA, Wh2, att2, bc2);

  // ---- projections (branches 1,2 only; branch 0 unused by output) ----
  gemm_nn<<<dim3(64,2),256,0,stream>>>(acc + (size_t)1*4096*FDIM, Wg + (size_t)1*FDIM*CDIM,
                                       bg + 1*CDIM, ng1, CDIM, 30, 1);
  gemm_nn<<<dim3(64,2),256,0,stream>>>(acc + (size_t)2*4096*FDIM, Wg + (size_t)2*FDIM*CDIM,
                                       bg + 2*CDIM, ng2, CDIM, 30, 1);
  gemm_nn<<<dim3(64,2),256,0,stream>>>(x, Wx + (size_t)1*FDIM*CDIM, bx + 1*CDIM, xs1, CDIM, 30, 1);
  gemm_nn<<<dim3(64,2),256,0,stream>>>(x, Wx + (size_t)2*FDIM*CDIM, bx + 2*CDIM, xs2, CDIM, 30, 1);

  // ---- result = [xs1 @ ng1^T , xs2 @ ng2^T]  (4096 x 8192) ----
  gemm_nt<<<dim3(64,64),256,0,stream>>>(xs1, ng1, outp, 8192, 0);
  gemm_nt<<<dim3(64,64),256,0,stream>>>(xs2, ng2, outp, 8192, 4096);

  // ---- second output: h (12288 x 256) ----
  hipMemcpyAsync(outp + (size_t)4096*8192, acc, SZ_H*4, hipMemcpyDeviceToDevice, stream);
}

// Round 2
// 1961.302 us; speedup vs baseline: 1.0610x; 1.0610x over previous
//
#include <hip/hip_runtime.h>
#include <cmath>

#define E_INC   393216
#define NN_     12288
#define MM_     16384
#define FDIM    256
#define CDIM    128

#define BM 64
#define BN 64
#define BK 16

__host__ __device__ inline int cntBase(int r){ return r<3 ? r*NN_ : 3*NN_ + (r-3)*MM_; }
__host__ __device__ inline int stBase(int r){ return r<3 ? r*(NN_+1) : 3*(NN_+1) + (r-3)*(MM_+1); }

__device__ __forceinline__ float lrelu(float v){ return v >= 0.0f ? v : 0.2f*v; }

struct Ptrs6 { const int* p[6]; };

// ---------------- CSR build ----------------
__global__ __launch_bounds__(256) void hist_kernel(Ptrs6 ip, int* __restrict__ cnt){
  int r = blockIdx.y;
  int e = blockIdx.x*256 + threadIdx.x;
  atomicAdd(&cnt[cntBase(r) + ip.p[r][e]], 1);
}

__global__ __launch_bounds__(1024) void scan_kernel(const int* __restrict__ cnt,
                                                    int* __restrict__ starts,
                                                    int* __restrict__ cur){
  int r = blockIdx.x;
  int nb = (r<3) ? NN_ : MM_;
  int cb = cntBase(r), sb = stBase(r);
  int t = threadIdx.x;
  int chunk = nb >> 10;               // 12 or 16
  int o = t*chunk;
  int s = 0;
  for (int j=0;j<chunk;++j) s += cnt[cb+o+j];
  __shared__ int sd[1024];
  sd[t] = s; __syncthreads();
  for (int ofs=1; ofs<1024; ofs<<=1){
    int v = (t>=ofs) ? sd[t-ofs] : 0;
    __syncthreads();
    sd[t] += v; __syncthreads();
  }
  int run = sd[t] - s;
  for (int j=0;j<chunk;++j){
    int c = cnt[cb+o+j];
    starts[sb+o+j] = run; cur[cb+o+j] = run;
    run += c;
  }
  if (t == 1023) starts[sb+nb] = run;
}

__global__ __launch_bounds__(256) void fill_kernel(Ptrs6 ip, int* __restrict__ cur,
                                                   int* __restrict__ lists){
  int r = blockIdx.y;
  int e = blockIdx.x*256 + threadIdx.x;
  int key = ip.p[r][e];
  int pos = atomicAdd(&cur[cntBase(r)+key], 1);
  lists[(size_t)r*E_INC + pos] = e;
}

// sort each bucket ascending -> accumulation order == numpy sequential order.
// One WAVE per bucket: 64-lane register bitonic sort (buckets are Poisson(32)/
// Poisson(24); len>64 is ~4e-6 rare -> lane-0 insertion fallback).
__global__ __launch_bounds__(256) void sortb_kernel(const int* __restrict__ starts,
                                                    int* __restrict__ lists){
  int r = blockIdx.y;
  int nb = (r<3) ? NN_ : MM_;
  int wid = (blockIdx.x*256 + threadIdx.x) >> 6;
  int lane = threadIdx.x & 63;
  if (wid >= nb) return;
  int sb = stBase(r);
  int lo = starts[sb+wid], hi = starts[sb+wid+1];
  int len = hi - lo;
  if (len <= 1) return;
  int* lst = lists + (size_t)r*E_INC;
  if (len <= 64){
    int v = (lane < len) ? lst[lo+lane] : 0x7fffffff;
#pragma unroll
    for (int k = 2; k <= 64; k <<= 1){
#pragma unroll
      for (int j = k>>1; j > 0; j >>= 1){
        int o = __shfl_xor(v, j);
        bool up    = ((lane & k) == 0);
        bool lower = ((lane & j) == 0);
        int mn = min(v,o), mx = max(v,o);
        v = (lower == up) ? mn : mx;
      }
    }
    if (lane < len) lst[lo+lane] = v;
  } else if (lane == 0) {
    for (int i=lo+1; i<hi; ++i){
      int key = lst[i]; int j = i-1;
      while (j>=lo && lst[j]>key){ lst[j+1]=lst[j]; --j; }
      lst[j+1]=key;
    }
  }
}

// ---------------- fp32 GEMMs ----------------
#define FMA4(i, a) \
  acc[i][0]=fmaf(a,bv.x,acc[i][0]); acc[i][1]=fmaf(a,bv.y,acc[i][1]); \
  acc[i][2]=fmaf(a,bv.z,acc[i][2]); acc[i][3]=fmaf(a,bv.w,acc[i][3]);

// C[rows x N] = A[rows x 256] @ W[seg][256 x N] (+bias) (opt leaky); ldc = N
__global__ __launch_bounds__(256)
void gemm_nn(const float* __restrict__ A, const float* __restrict__ W,
             const float* __restrict__ bias, float* __restrict__ C,
             int N, int segShift, int act)
{
  __shared__ alignas(16) float As[BK][BM+4];
  __shared__ alignas(16) float Bs[BK][BN+4];
  int t = threadIdx.x;
  int bm = blockIdx.x * BM;
  int bn = blockIdx.y * BN;
  int seg = bm >> segShift;
  const float* Wp = W + (size_t)seg * FDIM * N;
  int tx = t & 15, ty = t >> 4;
  int arow = t >> 2, akq = (t & 3) << 2;
  int brow = t >> 4, bcg = (t & 15) << 2;

  float acc[4][4] = {};
  for (int k0 = 0; k0 < FDIM; k0 += BK){
    float4 a4 = *(const float4*)(A + (size_t)(bm+arow)*FDIM + k0 + akq);
    As[akq+0][arow]=a4.x; As[akq+1][arow]=a4.y; As[akq+2][arow]=a4.z; As[akq+3][arow]=a4.w;
    float4 b4 = *(const float4*)(Wp + (size_t)(k0+brow)*N + bn + bcg);
    *(float4*)&Bs[brow][bcg] = b4;
    __syncthreads();
#pragma unroll
    for (int kk=0; kk<BK; ++kk){
      float4 av = *(const float4*)&As[kk][ty<<2];
      float4 bv = *(const float4*)&Bs[kk][tx<<2];
      FMA4(0, av.x) FMA4(1, av.y) FMA4(2, av.z) FMA4(3, av.w)
    }
    __syncthreads();
  }
  int c0 = bn + (tx<<2);
  float4 bb = make_float4(0.f,0.f,0.f,0.f);
  if (bias) bb = *(const float4*)(bias + (size_t)seg*N + c0);
#pragma unroll
  for (int i=0;i<4;++i){
    float4 o = make_float4(acc[i][0],acc[i][1],acc[i][2],acc[i][3]);
    if (bias){ o.x+=bb.x; o.y+=bb.y; o.z+=bb.z; o.w+=bb.w; }
    if (act){ o.x=lrelu(o.x); o.y=lrelu(o.y); o.z=lrelu(o.z); o.w=lrelu(o.w); }
    *(float4*)(C + (size_t)(bm+(ty<<2)+i)*N + c0) = o;
  }
}

// C[4096 x 4096] (+colOff into ldc-row) = A[4096 x 128] @ B[4096 x 128]^T
__global__ __launch_bounds__(256)
void gemm_nt(const float* __restrict__ A, const float* __restrict__ B,
             float* __restrict__ C, int ldc, int colOff)
{
  __shared__ alignas(16) float As[BK][BM+4];
  __shared__ alignas(16) float Bs[BK][BN+4];
  int t = threadIdx.x;
  int bm = blockIdx.x * BM;
  int bn = blockIdx.y * BN;
  int tx = t & 15, ty = t >> 4;
  int arow = t >> 2, akq = (t & 3) << 2;

  float acc[4][4] = {};
  for (int k0 = 0; k0 < CDIM; k0 += BK){
    float4 a4 = *(const float4*)(A + (size_t)(bm+arow)*CDIM + k0 + akq);
    As[akq+0][arow]=a4.x; As[akq+1][arow]=a4.y; As[akq+2][arow]=a4.z; As[akq+3][arow]=a4.w;
    float4 b4 = *(const float4*)(B + (size_t)(bn+arow)*CDIM + k0 + akq);
    Bs[akq+0][arow]=b4.x; Bs[akq+1][arow]=b4.y; Bs[akq+2][arow]=b4.z; Bs[akq+3][arow]=b4.w;
    __syncthreads();
#pragma unroll
    for (int kk=0; kk<BK; ++kk){
      float4 av = *(const float4*)&As[kk][ty<<2];
      float4 bv = *(const float4*)&Bs[kk][tx<<2];
      FMA4(0, av.x) FMA4(1, av.y) FMA4(2, av.z) FMA4(3, av.w)
    }
    __syncthreads();
  }
#pragma unroll
  for (int i=0;i<4;++i){
    float4 o = make_float4(acc[i][0],acc[i][1],acc[i][2],acc[i][3]);
    *(float4*)(C + (size_t)(bm+(ty<<2)+i)*ldc + colOff + bn + (tx<<2)) = o;
  }
}

// ---------------- attention scalar pipeline ----------------
// out[w] = dot(Mx[w,:256], vec)   (fp64 accumulate, one wave per row)
__global__ __launch_bounds__(256)
void rowdot(const float* __restrict__ Mx, const float* __restrict__ vec,
            float* __restrict__ out, int rows)
{
  int g = blockIdx.x*256 + threadIdx.x;
  int w = g >> 6, lane = g & 63;
  if (w >= rows) return;
  const float* r = Mx + (size_t)w*FDIM;
  double s = 0.0;
#pragma unroll
  for (int c=lane; c<FDIM; c+=64) s = fma((double)r[c], (double)vec[c], s);
  for (int ofs=32; ofs; ofs>>=1) s += __shfl_down(s, ofs);
  if (lane==0) out[w] = (float)s;
}

__global__ __launch_bounds__(256)
void node_stats(const int* __restrict__ starts, const int* __restrict__ list,
                const int* __restrict__ ei, const float* __restrict__ s1,
                const float* __restrict__ s2, const float* __restrict__ hw,
                float* __restrict__ amax, float* __restrict__ asum,
                float* __restrict__ dinv)
{
  int g = blockIdx.x*256 + threadIdx.x;
  int w = g >> 6, lane = g & 63;
  if (w >= NN_) return;
  int lo = starts[w], hi = starts[w+1];
  float s1n = s1[w];
  float mx = -INFINITY;
  for (int i=lo+lane; i<hi; i+=64){
    int e = list[i];
    mx = fmaxf(mx, lrelu(s1n + s2[ei[e]]));
  }
  for (int ofs=32; ofs; ofs>>=1) mx = fmaxf(mx, __shfl_xor(mx, ofs));
  if (lo == hi) mx = 0.0f;            // isfinite(amax) -> 0 for empty segments
  double se = 0.0, sd = 0.0;
  for (int i=lo+lane; i<hi; i+=64){
    int e = list[i]; int m = ei[e];
    float a = lrelu(s1n + s2[m]);
    se += (double)expf(a - mx);
    sd += (double)hw[m];
  }
  for (int ofs=32; ofs; ofs>>=1){ se += __shfl_xor(se, ofs); sd += __shfl_xor(sd, ofs); }
  if (lane==0){
    amax[w] = mx;
    asum[w] = (float)se;
    float D = (float)sd;
    dinv[w] = (D > 0.0f) ? 1.0f/D : 0.0f;
  }
}

__global__ __launch_bounds__(256)
void alpha_kernel(const int* __restrict__ ni, const int* __restrict__ ei,
                  const float* __restrict__ s1, const float* __restrict__ s2,
                  const float* __restrict__ amax, const float* __restrict__ asum,
                  float* __restrict__ alpha)
{
  int e = blockIdx.x*256 + threadIdx.x;
  int n = ni[e];
  float a = lrelu(s1[n] + s2[ei[e]]);
  alpha[e] = expf(a - amax[n]) / asum[n];
}

// ---------------- propagation (gather via CSR, np-order exact) ----------------
__global__ __launch_bounds__(256)
void m_kernel(const int* __restrict__ estarts, const int* __restrict__ elist,
              const int* __restrict__ ni, const float* __restrict__ alpha,
              const float* __restrict__ xl, float* __restrict__ m)
{
  int g = blockIdx.x*256 + threadIdx.x;
  int w = g >> 6, lane = g & 63;
  if (w >= MM_) return;
  int lo = estarts[w], hi = estarts[w+1];
  float binv = (hi > lo) ? 1.0f/(float)(hi-lo) : 0.0f;
  float ax=0.f, ay=0.f, az=0.f, aw=0.f;
  int col = lane << 2;
  for (int i=lo; i<hi; ++i){
    int e = elist[i];
    float c = __fmul_rn(binv, alpha[e]);
    const float4 x4 = *(const float4*)(xl + (size_t)ni[e]*FDIM + col);
    ax = __fadd_rn(ax, __fmul_rn(c, x4.x));
    ay = __fadd_rn(ay, __fmul_rn(c, x4.y));
    az = __fadd_rn(az, __fmul_rn(c, x4.z));
    aw = __fadd_rn(aw, __fmul_rn(c, x4.w));
  }
  *(float4*)(m + (size_t)w*FDIM + col) = make_float4(ax,ay,az,aw);
}

__global__ __launch_bounds__(256)
void out_kernel(const int* __restrict__ nstarts, const int* __restrict__ nlist,
                const int* __restrict__ ei, const float* __restrict__ alpha,
                const float* __restrict__ dinv, const float* __restrict__ m,
                const float* __restrict__ bias, float* __restrict__ accb,
                int first, int finalAct)
{
  int g = blockIdx.x*256 + threadIdx.x;
  int w = g >> 6, lane = g & 63;
  if (w >= NN_) return;
  int lo = nstarts[w], hi = nstarts[w+1];
  float dv = dinv[w];
  float ax=0.f, ay=0.f, az=0.f, aw=0.f;
  int col = lane << 2;
  for (int i=lo; i<hi; ++i){
    int e = nlist[i];
    float c = __fmul_rn(dv, alpha[e]);
    const float4 m4 = *(const float4*)(m + (size_t)ei[e]*FDIM + col);
    ax = __fadd_rn(ax, __fmul_rn(c, m4.x));
    ay = __fadd_rn(ay, __fmul_rn(c, m4.y));
    az = __fadd_rn(az, __fmul_rn(c, m4.z));
    aw = __fadd_rn(aw, __fmul_rn(c, m4.w));
  }
  const float4 b4 = *(const float4*)(bias + col);
  ax = __fadd_rn(ax, b4.x); ay = __fadd_rn(ay, b4.y);
  az = __fadd_rn(az, b4.z); aw = __fadd_rn(aw, b4.w);
  float* p = accb + (size_t)w*FDIM + col;
  if (!first){
    float4 pr = *(const float4*)p;
    ax = __fadd_rn(pr.x, ax); ay = __fadd_rn(pr.y, ay);
    az = __fadd_rn(pr.z, az); aw = __fadd_rn(pr.w, aw);
  }
  if (finalAct){ ax=lrelu(ax); ay=lrelu(ay); az=lrelu(az); aw=lrelu(aw); }
  *(float4*)p = make_float4(ax,ay,az,aw);
}

// ---------------- host orchestration ----------------
extern "C" void kernel_launch(void* const* d_in, const int* in_sizes, int n_in,
                              void* d_out, int out_size, void* d_ws, size_t ws_size,
                              hipStream_t stream)
{
  (void)in_sizes; (void)n_in; (void)out_size; (void)ws_size;
  const float* g     = (const float*)d_in[0];
  const float* x     = (const float*)d_in[1];
  const float* hw    = (const float*)d_in[2];
  const float* hattr = (const float*)d_in[3];
  const int* ni[3]   = {(const int*)d_in[4], (const int*)d_in[6], (const int*)d_in[8]};
  const int* ei[3]   = {(const int*)d_in[5], (const int*)d_in[7], (const int*)d_in[9]};
  const float* W0  = (const float*)d_in[10];
  const float* b0  = (const float*)d_in[11];
  const float* Wh1 = (const float*)d_in[12];
  const float* att1= (const float*)d_in[13];
  const float* bc1 = (const float*)d_in[14];
  const float* W1  = (const float*)d_in[15];
  const float* b1  = (const float*)d_in[16];
  const float* Wh2 = (const float*)d_in[17];
  const float* att2= (const float*)d_in[18];
  const float* bc2 = (const float*)d_in[19];
  const float* Wg  = (const float*)d_in[20];
  const float* bg  = (const float*)d_in[21];
  const float* Wx  = (const float*)d_in[22];
  const float* bx  = (const float*)d_in[23];
  float* outp = (float*)d_out;

  // workspace layout (256B-aligned slabs)
  char* base = (char*)d_ws;
  size_t off = 0;
  auto alloc = [&](size_t bytes)->void*{
    void* p = base + off;
    off = (off + bytes + 255) & ~(size_t)255;
    return p;
  };
  const size_t SZ_H = (size_t)NN_*FDIM;
  float* hA    = (float*)alloc(SZ_H*4);
  float* xl    = (float*)alloc(SZ_H*4);
  float* acc   = (float*)alloc(SZ_H*4);
  float* mbuf  = (float*)alloc((size_t)MM_*FDIM*4);
  float* alphab= (float*)alloc((size_t)E_INC*4);
  float* s1    = (float*)alloc(NN_*4);
  float* s2    = (float*)alloc(MM_*4);
  float* vv    = (float*)alloc(FDIM*4);
  float* amax  = (float*)alloc(NN_*4);
  float* asum  = (float*)alloc(NN_*4);
  float* dinvb = (float*)alloc(NN_*4);
  float* ng1   = (float*)alloc((size_t)4096*CDIM*4);
  float* ng2   = (float*)alloc((size_t)4096*CDIM*4);
  float* xs1   = (float*)alloc((size_t)4096*CDIM*4);
  float* xs2   = (float*)alloc((size_t)4096*CDIM*4);
  int*   cnt   = (int*)alloc((size_t)(3*NN_+3*MM_)*4);
  int*   cur   = (int*)alloc((size_t)(3*NN_+3*MM_)*4);
  int*   stb   = (int*)alloc((size_t)(3*(NN_+1)+3*(MM_+1))*4);
  int*   lists = (int*)alloc((size_t)6*E_INC*4);

  // ---- CSR build (shared by both hyper layers) ----
  hipMemsetAsync(cnt, 0, (size_t)(3*NN_+3*MM_)*4, stream);
  Ptrs6 ip{{ni[0],ni[1],ni[2],ei[0],ei[1],ei[2]}};
  hist_kernel <<<dim3(E_INC/256,6),256,0,stream>>>(ip, cnt);
  scan_kernel <<<6,1024,0,stream>>>(cnt, stb, cur);
  fill_kernel <<<dim3(E_INC/256,6),256,0,stream>>>(ip, cur, lists);
  sortb_kernel<<<dim3(4096,6),256,0,stream>>>(stb, lists);

  // ---- layer0: h = leaky(g @ W0[seg] + b0[seg]) ----
  gemm_nn<<<dim3(192,4),256,0,stream>>>(g, W0, b0, hA, FDIM, 12, 1);

  auto hyper = [&](const float* hin, const float* Whs, const float* atts, const float* bcs){
    for (int k=0;k<3;++k){
      const float* Wk   = Whs + (size_t)k*FDIM*FDIM;
      const float* attA = atts + (size_t)k*2*FDIM;
      const float* attB = attA + FDIM;
      const int* nst = stb + stBase(k);
      const int* nls = lists + (size_t)k*E_INC;
      const int* est = stb + stBase(3+k);
      const int* els = lists + (size_t)(3+k)*E_INC;
      gemm_nn    <<<dim3(192,4),256,0,stream>>>(hin, Wk, nullptr, xl, FDIM, 30, 0);
      rowdot     <<<64,  256,0,stream>>>(Wk, attB, vv, FDIM);          // v = W @ attB
      rowdot     <<<3072,256,0,stream>>>(xl, attA, s1, NN_);
      rowdot     <<<4096,256,0,stream>>>(hattr, vv, s2, MM_);
      node_stats <<<3072,256,0,stream>>>(nst, nls, ei[k], s1, s2, hw, amax, asum, dinvb);
      alpha_kernel<<<E_INC/256,256,0,stream>>>(ni[k], ei[k], s1, s2, amax, asum, alphab);
      m_kernel   <<<4096,256,0,stream>>>(est, els, ni[k], alphab, xl, mbuf);
      out_kernel <<<3072,256,0,stream>>>(nst, nls, ei[k], alphab, dinvb, mbuf,
                                         bcs + (size_t)k*FDIM, acc, k==0, k==2);
    }
  };

  // ---- hyper1 (reads hA, result -> acc, leaky fused on last branch) ----
  hyper(hA, Wh1, att1, bc1);
  // ---- layer1: hA = leaky(acc @ W1[seg] + b1[seg]) ----
  gemm_nn<<<dim3(192,4),256,0,stream>>>(acc, W1, b1, hA, FDIM, 12, 1);
  // ---- hyper2 (reads hA, result -> acc = final h) ----
  hyper(hA, Wh2, att2, bc2);

  // ---- projections (branches 1,2 only; branch 0 unused by output) ----
  gemm_nn<<<dim3(64,2),256,0,stream>>>(acc + (size_t)1*4096*FDIM, Wg + (size_t)1*FDIM*CDIM,
                                       bg + 1*CDIM, ng1, CDIM, 30, 1);
  gemm_nn<<<dim3(64,2),256,0,stream>>>(acc + (size_t)2*4096*FDIM, Wg + (size_t)2*FDIM*CDIM,
                                       bg + 2*CDIM, ng2, CDIM, 30, 1);
  gemm_nn<<<dim3(64,2),256,0,stream>>>(x, Wx + (size_t)1*FDIM*CDIM, bx + 1*CDIM, xs1, CDIM, 30, 1);
  gemm_nn<<<dim3(64,2),256,0,stream>>>(x, Wx + (size_t)2*FDIM*CDIM, bx + 2*CDIM, xs2, CDIM, 30, 1);

  // ---- result = [xs1 @ ng1^T , xs2 @ ng2^T]  (4096 x 8192) ----
  gemm_nt<<<dim3(64,64),256,0,stream>>>(xs1, ng1, outp, 8192, 0);
  gemm_nt<<<dim3(64,64),256,0,stream>>>(xs2, ng2, outp, 8192, 4096);

  // ---- second output: h (12288 x 256) ----
  hipMemcpyAsync(outp + (size_t)4096*8192, acc, SZ_H*4, hipMemcpyDeviceToDevice, stream);
}

// Round 3
// 1829.484 us; speedup vs baseline: 1.1375x; 1.0721x over previous
//
#include <hip/hip_runtime.h>
#include <cmath>

#define E_INC   393216
#define NN_     12288
#define MM_     16384
#define FDIM    256
#define CDIM    128
#define PKEYS   128
#define LCAP    6144

__host__ __device__ inline int stBase(int r){ return r<3 ? r*(NN_+1) : 3*(NN_+1) + (r-3)*(MM_+1); }
__host__ __device__ inline int nParts(int r){ return (r<3 ? NN_ : MM_) / PKEYS; }  // 96 or 128

__device__ __forceinline__ float lrelu(float v){ return v >= 0.0f ? v : 0.2f*v; }

struct Ptrs6 { const int* p[6]; };

// ---------------- CSR build: two-level partition (write-locality) ----------------
// A1: coarse histogram over key>>7.  grid (96, 6) x 256
__global__ __launch_bounds__(256) void coarse_hist(Ptrs6 keys, int* __restrict__ ccnt){
  __shared__ int h[PKEYS];
  int r = blockIdx.y, t = threadIdx.x;
  if (t < PKEYS) h[t] = 0;
  __syncthreads();
  int base = blockIdx.x * 4096;
  const int* ka = keys.p[r];
  for (int j=0;j<16;++j) atomicAdd(&h[ka[base + j*256 + t] >> 7], 1);
  __syncthreads();
  if (t < PKEYS) atomicAdd(&ccnt[r*PKEYS + t], h[t]);
}

// A2: exclusive scan of coarse counts.  grid 6 x 128
__global__ __launch_bounds__(128) void coarse_scan(const int* __restrict__ ccnt,
                                                   int* __restrict__ cstart,
                                                   int* __restrict__ ccur){
  int r = blockIdx.x, t = threadIdx.x;
  int P = nParts(r);
  int c = (t < P) ? ccnt[r*PKEYS + t] : 0;
  __shared__ int sd[128];
  sd[t] = c; __syncthreads();
  for (int ofs=1; ofs<128; ofs<<=1){
    int v = (t>=ofs) ? sd[t-ofs] : 0;
    __syncthreads(); sd[t] += v; __syncthreads();
  }
  int excl = sd[t] - c;
  cstart[r*129 + t] = excl;
  ccur[r*PKEYS + t] = excl;
  if (t == 127) cstart[r*129 + 128] = sd[127];
}

// A3: scatter elements into coarse partition regions (blockwise reserved -> 128B chunks)
__global__ __launch_bounds__(256) void part_scatter(Ptrs6 keys, int* __restrict__ ccur,
                                                    int* __restrict__ pbuf){
  __shared__ int h[PKEYS];
  __shared__ int cur[PKEYS];
  int r = blockIdx.y, t = threadIdx.x;
  if (t < PKEYS) h[t] = 0;
  __syncthreads();
  int base = blockIdx.x * 4096;
  const int* ka = keys.p[r];
  int myk[16];
  for (int j=0;j<16;++j){
    myk[j] = ka[base + j*256 + t] >> 7;
    atomicAdd(&h[myk[j]], 1);
  }
  __syncthreads();
  if (t < PKEYS) cur[t] = atomicAdd(&ccur[r*PKEYS + t], h[t]);
  __syncthreads();
  int* pb = pbuf + (size_t)r * E_INC;
  for (int j=0;j<16;++j){
    int pos = atomicAdd(&cur[myk[j]], 1);
    pb[pos] = base + j*256 + t;
  }
}

// B: per-partition fine CSR build in LDS; coalesced lists/starts writes.
__global__ __launch_bounds__(256) void fine_build(Ptrs6 keys, const int* __restrict__ cstart,
                                                  const int* __restrict__ pbuf,
                                                  int* __restrict__ starts,
                                                  int* __restrict__ lists){
  __shared__ unsigned short kb[LCAP];
  __shared__ int ob[LCAP];
  __shared__ int h[PKEYS], ls[PKEYS], lc[PKEYS];
  int r = blockIdx.y, p = blockIdx.x, t = threadIdx.x;
  int P = nParts(r);
  if (p >= P) return;
  int lo = cstart[r*129 + p], hi = cstart[r*129 + p + 1];
  int len = hi - lo;
  if (t < PKEYS) h[t] = 0;
  __syncthreads();
  const int* ka = keys.p[r];
  const int* pb = pbuf + (size_t)r * E_INC;
  int* lst = lists + (size_t)r * E_INC;
  int kbase = p << 7;
  int sb = stBase(r);
  if (len <= LCAP){
    for (int i=t; i<len; i+=256){
      int e = pb[lo+i];
      int k = ka[e] - kbase;
      kb[i] = (unsigned short)k;
      atomicAdd(&h[k], 1);
    }
    __syncthreads();
    if (t == 0){ int run = 0; for (int k=0;k<PKEYS;++k){ ls[k]=run; lc[k]=run; run+=h[k]; } }
    __syncthreads();
    for (int i=t; i<len; i+=256){
      int pos = atomicAdd(&lc[kb[i]], 1);
      ob[pos] = pb[lo+i];
    }
    __syncthreads();
    for (int i=t; i<len; i+=256) lst[lo+i] = ob[i];
    if (t < PKEYS) starts[sb + kbase + t] = lo + ls[t];
  } else {
    // astronomically-rare fallback: same algorithm, direct global scatter
    for (int i=t; i<len; i+=256) atomicAdd(&h[ka[pb[lo+i]] - kbase], 1);
    __syncthreads();
    if (t == 0){ int run = 0; for (int k=0;k<PKEYS;++k){ ls[k]=run; lc[k]=run; run+=h[k]; } }
    __syncthreads();
    for (int i=t; i<len; i+=256){
      int e = pb[lo+i];
      int pos = atomicAdd(&lc[ka[e] - kbase], 1);
      lst[lo+pos] = e;
    }
    if (t < PKEYS) starts[sb + kbase + t] = lo + ls[t];
  }
  if (p == P-1 && t == 0) starts[sb + (r<3 ? NN_ : MM_)] = hi;
}

// sort each bucket ascending -> accumulation order == numpy sequential order.
__global__ __launch_bounds__(256) void sortb_kernel(const int* __restrict__ starts,
                                                    int* __restrict__ lists){
  int r = blockIdx.y;
  int nb = (r<3) ? NN_ : MM_;
  int wid = (blockIdx.x*256 + threadIdx.x) >> 6;
  int lane = threadIdx.x & 63;
  if (wid >= nb) return;
  int sb = stBase(r);
  int lo = starts[sb+wid], hi = starts[sb+wid+1];
  int len = hi - lo;
  if (len <= 1) return;
  int* lst = lists + (size_t)r*E_INC;
  if (len <= 64){
    int v = (lane < len) ? lst[lo+lane] : 0x7fffffff;
#pragma unroll
    for (int k = 2; k <= 64; k <<= 1){
#pragma unroll
      for (int j = k>>1; j > 0; j >>= 1){
        int o = __shfl_xor(v, j);
        bool up    = ((lane & k) == 0);
        bool lower = ((lane & j) == 0);
        int mn = min(v,o), mx = max(v,o);
        v = (lower == up) ? mn : mx;
      }
    }
    if (lane < len) lst[lo+lane] = v;
  } else if (lane == 0) {
    for (int i=lo+1; i<hi; ++i){
      int key = lst[i]; int j = i-1;
      while (j>=lo && lst[j]>key){ lst[j+1]=lst[j]; --j; }
      lst[j+1]=key;
    }
  }
}

// ---------------- fp32 GEMMs ----------------
// C[rows x N] = A[rows x 256] @ W[seg][256 x N] (+bias)(opt leaky). BM=128,BN=64,8x4/thread.
__global__ __launch_bounds__(256)
void gemm_nn(const float* __restrict__ A, const float* __restrict__ W,
             const float* __restrict__ bias, float* __restrict__ C,
             int N, int segShift, int act)
{
  __shared__ alignas(16) float As[16][132];
  __shared__ alignas(16) float Bs[16][68];
  int t = threadIdx.x;
  int bm = blockIdx.x * 128;
  int bn = blockIdx.y * 64;
  int seg = bm >> segShift;
  const float* Wp = W + (size_t)seg * FDIM * N;
  int tx = t & 15, ty = t >> 4;
  int arow = t >> 1, akq = (t & 1) << 3;
  int brow = t >> 4, bcol = (t & 15) << 2;

  float acc[8][4] = {};
  for (int k0 = 0; k0 < FDIM; k0 += 16){
    const float* ap = A + (size_t)(bm+arow)*FDIM + k0 + akq;
    float4 a0 = *(const float4*)(ap);
    float4 a1 = *(const float4*)(ap + 4);
    As[akq+0][arow]=a0.x; As[akq+1][arow]=a0.y; As[akq+2][arow]=a0.z; As[akq+3][arow]=a0.w;
    As[akq+4][arow]=a1.x; As[akq+5][arow]=a1.y; As[akq+6][arow]=a1.z; As[akq+7][arow]=a1.w;
    *(float4*)&Bs[brow][bcol] = *(const float4*)(Wp + (size_t)(k0+brow)*N + bn + bcol);
    __syncthreads();
#pragma unroll
    for (int kk=0; kk<16; ++kk){
      float4 x0 = *(const float4*)&As[kk][ty<<3];
      float4 x1 = *(const float4*)&As[kk][(ty<<3)+4];
      float4 bv = *(const float4*)&Bs[kk][tx<<2];
      float af[8] = {x0.x,x0.y,x0.z,x0.w,x1.x,x1.y,x1.z,x1.w};
      float bf[4] = {bv.x,bv.y,bv.z,bv.w};
#pragma unroll
      for (int i=0;i<8;++i)
#pragma unroll
        for (int j=0;j<4;++j) acc[i][j] = fmaf(af[i], bf[j], acc[i][j]);
    }
    __syncthreads();
  }
  int c0 = bn + (tx<<2);
  float4 bb = make_float4(0.f,0.f,0.f,0.f);
  if (bias) bb = *(const float4*)(bias + (size_t)seg*N + c0);
#pragma unroll
  for (int i=0;i<8;++i){
    float4 o = make_float4(acc[i][0],acc[i][1],acc[i][2],acc[i][3]);
    if (bias){ o.x+=bb.x; o.y+=bb.y; o.z+=bb.z; o.w+=bb.w; }
    if (act){ o.x=lrelu(o.x); o.y=lrelu(o.y); o.z=lrelu(o.z); o.w=lrelu(o.w); }
    *(float4*)(C + (size_t)(bm+(ty<<3)+i)*N + c0) = o;
  }
}

// C[4096 x 4096](+colOff) = A[4096 x 128] @ B[4096 x 128]^T. BM=BN=128, 8x8/thread.
__global__ __launch_bounds__(256)
void gemm_nt(const float* __restrict__ A, const float* __restrict__ B,
             float* __restrict__ C, int ldc, int colOff)
{
  __shared__ alignas(16) float As[16][132];
  __shared__ alignas(16) float Bs[16][132];
  int t = threadIdx.x;
  int bm = blockIdx.x * 128;
  int bn = blockIdx.y * 128;
  int tx = t & 15, ty = t >> 4;
  int arow = t >> 1, akq = (t & 1) << 3;

  float acc[8][8] = {};
  for (int k0 = 0; k0 < CDIM; k0 += 16){
    const float* ap = A + (size_t)(bm+arow)*CDIM + k0 + akq;
    float4 a0 = *(const float4*)(ap);
    float4 a1 = *(const float4*)(ap + 4);
    As[akq+0][arow]=a0.x; As[akq+1][arow]=a0.y; As[akq+2][arow]=a0.z; As[akq+3][arow]=a0.w;
    As[akq+4][arow]=a1.x; As[akq+5][arow]=a1.y; As[akq+6][arow]=a1.z; As[akq+7][arow]=a1.w;
    const float* bp = B + (size_t)(bn+arow)*CDIM + k0 + akq;
    float4 b0 = *(const float4*)(bp);
    float4 b1 = *(const float4*)(bp + 4);
    Bs[akq+0][arow]=b0.x; Bs[akq+1][arow]=b0.y; Bs[akq+2][arow]=b0.z; Bs[akq+3][arow]=b0.w;
    Bs[akq+4][arow]=b1.x; Bs[akq+5][arow]=b1.y; Bs[akq+6][arow]=b1.z; Bs[akq+7][arow]=b1.w;
    __syncthreads();
#pragma unroll
    for (int kk=0; kk<16; ++kk){
      float4 x0 = *(const float4*)&As[kk][ty<<3];
      float4 x1 = *(const float4*)&As[kk][(ty<<3)+4];
      float4 y0 = *(const float4*)&Bs[kk][tx<<3];
      float4 y1 = *(const float4*)&Bs[kk][(tx<<3)+4];
      float af[8] = {x0.x,x0.y,x0.z,x0.w,x1.x,x1.y,x1.z,x1.w};
      float bf[8] = {y0.x,y0.y,y0.z,y0.w,y1.x,y1.y,y1.z,y1.w};
#pragma unroll
      for (int i=0;i<8;++i)
#pragma unroll
        for (int j=0;j<8;++j) acc[i][j] = fmaf(af[i], bf[j], acc[i][j]);
    }
    __syncthreads();
  }
  int c0 = colOff + bn + (tx<<3);
#pragma unroll
  for (int i=0;i<8;++i){
    float* cp = C + (size_t)(bm+(ty<<3)+i)*ldc + c0;
    *(float4*)(cp)   = make_float4(acc[i][0],acc[i][1],acc[i][2],acc[i][3]);
    *(float4*)(cp+4) = make_float4(acc[i][4],acc[i][5],acc[i][6],acc[i][7]);
  }
}

// ---------------- attention scalar pipeline ----------------
__global__ __launch_bounds__(256)
void rowdot(const float* __restrict__ Mx, const float* __restrict__ vec,
            float* __restrict__ out, int rows)
{
  int g = blockIdx.x*256 + threadIdx.x;
  int w = g >> 6, lane = g & 63;
  if (w >= rows) return;
  const float* r = Mx + (size_t)w*FDIM;
  double s = 0.0;
#pragma unroll
  for (int c=lane; c<FDIM; c+=64) s = fma((double)r[c], (double)vec[c], s);
  for (int ofs=32; ofs; ofs>>=1) s += __shfl_down(s, ofs);
  if (lane==0) out[w] = (float)s;
}

__global__ __launch_bounds__(256)
void node_stats(const int* __restrict__ starts, const int* __restrict__ list,
                const int* __restrict__ ei, const float* __restrict__ s1,
                const float* __restrict__ s2, const float* __restrict__ hw,
                float* __restrict__ amax, float* __restrict__ asum,
                float* __restrict__ dinv)
{
  int g = blockIdx.x*256 + threadIdx.x;
  int w = g >> 6, lane = g & 63;
  if (w >= NN_) return;
  int lo = starts[w], hi = starts[w+1];
  float s1n = s1[w];
  float mx = -INFINITY;
  for (int i=lo+lane; i<hi; i+=64){
    int e = list[i];
    mx = fmaxf(mx, lrelu(s1n + s2[ei[e]]));
  }
  for (int ofs=32; ofs; ofs>>=1) mx = fmaxf(mx, __shfl_xor(mx, ofs));
  if (lo == hi) mx = 0.0f;
  double se = 0.0, sd = 0.0;
  for (int i=lo+lane; i<hi; i+=64){
    int e = list[i]; int m = ei[e];
    float a = lrelu(s1n + s2[m]);
    se += (double)expf(a - mx);
    sd += (double)hw[m];
  }
  for (int ofs=32; ofs; ofs>>=1){ se += __shfl_xor(se, ofs); sd += __shfl_xor(sd, ofs); }
  if (lane==0){
    amax[w] = mx;
    asum[w] = (float)se;
    float D = (float)sd;
    dinv[w] = (D > 0.0f) ? 1.0f/D : 0.0f;
  }
}

__global__ __launch_bounds__(256)
void alpha_kernel(const int* __restrict__ ni, const int* __restrict__ ei,
                  const float* __restrict__ s1, const float* __restrict__ s2,
                  const float* __restrict__ amax, const float* __restrict__ asum,
                  float* __restrict__ alpha)
{
  int e = blockIdx.x*256 + threadIdx.x;
  int n = ni[e];
  float a = lrelu(s1[n] + s2[ei[e]]);
  alpha[e] = expf(a - amax[n]) / asum[n];
}

// ---------------- propagation (gather via CSR, np-order exact) ----------------
__global__ __launch_bounds__(256)
void m_kernel(const int* __restrict__ estarts, const int* __restrict__ elist,
              const int* __restrict__ ni, const float* __restrict__ alpha,
              const float* __restrict__ xl, float* __restrict__ m)
{
  int g = blockIdx.x*256 + threadIdx.x;
  int w = g >> 6, lane = g & 63;
  if (w >= MM_) return;
  int lo = estarts[w], hi = estarts[w+1];
  float binv = (hi > lo) ? 1.0f/(float)(hi-lo) : 0.0f;
  float ax=0.f, ay=0.f, az=0.f, aw=0.f;
  int col = lane << 2;
  for (int i=lo; i<hi; ++i){
    int e = elist[i];
    float c = __fmul_rn(binv, alpha[e]);
    const float4 x4 = *(const float4*)(xl + (size_t)ni[e]*FDIM + col);
    ax = __fadd_rn(ax, __fmul_rn(c, x4.x));
    ay = __fadd_rn(ay, __fmul_rn(c, x4.y));
    az = __fadd_rn(az, __fmul_rn(c, x4.z));
    aw = __fadd_rn(aw, __fmul_rn(c, x4.w));
  }
  *(float4*)(m + (size_t)w*FDIM + col) = make_float4(ax,ay,az,aw);
}

__global__ __launch_bounds__(256)
void out_kernel(const int* __restrict__ nstarts, const int* __restrict__ nlist,
                const int* __restrict__ ei, const float* __restrict__ alpha,
                const float* __restrict__ dinv, const float* __restrict__ m,
                const float* __restrict__ bias, float* __restrict__ accb,
                int first, int finalAct)
{
  int g = blockIdx.x*256 + threadIdx.x;
  int w = g >> 6, lane = g & 63;
  if (w >= NN_) return;
  int lo = nstarts[w], hi = nstarts[w+1];
  float dv = dinv[w];
  float ax=0.f, ay=0.f, az=0.f, aw=0.f;
  int col = lane << 2;
  for (int i=lo; i<hi; ++i){
    int e = nlist[i];
    float c = __fmul_rn(dv, alpha[e]);
    const float4 m4 = *(const float4*)(m + (size_t)ei[e]*FDIM + col);
    ax = __fadd_rn(ax, __fmul_rn(c, m4.x));
    ay = __fadd_rn(ay, __fmul_rn(c, m4.y));
    az = __fadd_rn(az, __fmul_rn(c, m4.z));
    aw = __fadd_rn(aw, __fmul_rn(c, m4.w));
  }
  const float4 b4 = *(const float4*)(bias + col);
  ax = __fadd_rn(ax, b4.x); ay = __fadd_rn(ay, b4.y);
  az = __fadd_rn(az, b4.z); aw = __fadd_rn(aw, b4.w);
  float* p = accb + (size_t)w*FDIM + col;
  if (!first){
    float4 pr = *(const float4*)p;
    ax = __fadd_rn(pr.x, ax); ay = __fadd_rn(pr.y, ay);
    az = __fadd_rn(pr.z, az); aw = __fadd_rn(pr.w, aw);
  }
  if (finalAct){ ax=lrelu(ax); ay=lrelu(ay); az=lrelu(az); aw=lrelu(aw); }
  *(float4*)p = make_float4(ax,ay,az,aw);
}

// ---------------- host orchestration ----------------
extern "C" void kernel_launch(void* const* d_in, const int* in_sizes, int n_in,
                              void* d_out, int out_size, void* d_ws, size_t ws_size,
                              hipStream_t stream)
{
  (void)in_sizes; (void)n_in; (void)out_size; (void)ws_size;
  const float* g     = (const float*)d_in[0];
  const float* x     = (const float*)d_in[1];
  const float* hw    = (const float*)d_in[2];
  const float* hattr = (const float*)d_in[3];
  const int* ni[3]   = {(const int*)d_in[4], (const int*)d_in[6], (const int*)d_in[8]};
  const int* ei[3]   = {(const int*)d_in[5], (const int*)d_in[7], (const int*)d_in[9]};
  const float* W0  = (const float*)d_in[10];
  const float* b0  = (const float*)d_in[11];
  const float* Wh1 = (const float*)d_in[12];
  const float* att1= (const float*)d_in[13];
  const float* bc1 = (const float*)d_in[14];
  const float* W1  = (const float*)d_in[15];
  const float* b1  = (const float*)d_in[16];
  const float* Wh2 = (const float*)d_in[17];
  const float* att2= (const float*)d_in[18];
  const float* bc2 = (const float*)d_in[19];
  const float* Wg  = (const float*)d_in[20];
  const float* bg  = (const float*)d_in[21];
  const float* Wx  = (const float*)d_in[22];
  const float* bx  = (const float*)d_in[23];
  float* outp = (float*)d_out;

  char* base = (char*)d_ws;
  size_t off = 0;
  auto alloc = [&](size_t bytes)->void*{
    void* p = base + off;
    off = (off + bytes + 255) & ~(size_t)255;
    return p;
  };
  const size_t SZ_H = (size_t)NN_*FDIM;
  float* hA    = (float*)alloc(SZ_H*4);
  float* xl    = (float*)alloc(SZ_H*4);
  float* acc   = (float*)alloc(SZ_H*4);
  float* mbuf  = (float*)alloc((size_t)MM_*FDIM*4);   // also aliased as pbuf during CSR build
  float* alphab= (float*)alloc((size_t)E_INC*4);
  float* s1    = (float*)alloc(NN_*4);
  float* s2    = (float*)alloc(MM_*4);
  float* vv    = (float*)alloc(FDIM*4);
  float* amax  = (float*)alloc(NN_*4);
  float* asum  = (float*)alloc(NN_*4);
  float* dinvb = (float*)alloc(NN_*4);
  float* ng1   = (float*)alloc((size_t)4096*CDIM*4);
  float* ng2   = (float*)alloc((size_t)4096*CDIM*4);
  float* xs1   = (float*)alloc((size_t)4096*CDIM*4);
  float* xs2   = (float*)alloc((size_t)4096*CDIM*4);
  int*   ccnt  = (int*)alloc((size_t)6*PKEYS*4);
  int*   ccur  = (int*)alloc((size_t)6*PKEYS*4);
  int*   cstart= (int*)alloc((size_t)6*129*4);
  int*   stb   = (int*)alloc((size_t)(3*(NN_+1)+3*(MM_+1))*4);
  int*   lists = (int*)alloc((size_t)6*E_INC*4);
  int*   pbuf  = (int*)mbuf;   // alias: CSR build finishes before mbuf is used

  // ---- CSR build (shared by both hyper layers) ----
  hipMemsetAsync(ccnt, 0, (size_t)6*PKEYS*4, stream);
  Ptrs6 ip{{ni[0],ni[1],ni[2],ei[0],ei[1],ei[2]}};
  coarse_hist <<<dim3(96,6),256,0,stream>>>(ip, ccnt);
  coarse_scan <<<6,128,0,stream>>>(ccnt, cstart, ccur);
  part_scatter<<<dim3(96,6),256,0,stream>>>(ip, ccur, pbuf);
  fine_build  <<<dim3(128,6),256,0,stream>>>(ip, cstart, pbuf, stb, lists);
  sortb_kernel<<<dim3(4096,6),256,0,stream>>>(stb, lists);

  // ---- layer0: h = leaky(g @ W0[seg] + b0[seg]) ----
  gemm_nn<<<dim3(96,4),256,0,stream>>>(g, W0, b0, hA, FDIM, 12, 1);

  auto hyper = [&](const float* hin, const float* Whs, const float* atts, const float* bcs){
    for (int k=0;k<3;++k){
      const float* Wk   = Whs + (size_t)k*FDIM*FDIM;
      const float* attA = atts + (size_t)k*2*FDIM;
      const float* attB = attA + FDIM;
      const int* nst = stb + stBase(k);
      const int* nls = lists + (size_t)k*E_INC;
      const int* est = stb + stBase(3+k);
      const int* els = lists + (size_t)(3+k)*E_INC;
      gemm_nn    <<<dim3(96,4),256,0,stream>>>(hin, Wk, nullptr, xl, FDIM, 30, 0);
      rowdot     <<<64,  256,0,stream>>>(Wk, attB, vv, FDIM);          // v = W @ attB
      rowdot     <<<3072,256,0,stream>>>(xl, attA, s1, NN_);
      rowdot     <<<4096,256,0,stream>>>(hattr, vv, s2, MM_);
      node_stats <<<3072,256,0,stream>>>(nst, nls, ei[k], s1, s2, hw, amax, asum, dinvb);
      alpha_kernel<<<E_INC/256,256,0,stream>>>(ni[k], ei[k], s1, s2, amax, asum, alphab);
      m_kernel   <<<4096,256,0,stream>>>(est, els, ni[k], alphab, xl, mbuf);
      out_kernel <<<3072,256,0,stream>>>(nst, nls, ei[k], alphab, dinvb, mbuf,
                                         bcs + (size_t)k*FDIM, acc, k==0, k==2);
    }
  };

  hyper(hA, Wh1, att1, bc1);
  gemm_nn<<<dim3(96,4),256,0,stream>>>(acc, W1, b1, hA, FDIM, 12, 1);
  hyper(hA, Wh2, att2, bc2);

  // ---- projections (branches 1,2 only; branch 0 unused by output) ----
  gemm_nn<<<dim3(32,2),256,0,stream>>>(acc + (size_t)1*4096*FDIM, Wg + (size_t)1*FDIM*CDIM,
                                       bg + 1*CDIM, ng1, CDIM, 30, 1);
  gemm_nn<<<dim3(32,2),256,0,stream>>>(acc + (size_t)2*4096*FDIM, Wg + (size_t)2*FDIM*CDIM,
                                       bg + 2*CDIM, ng2, CDIM, 30, 1);
  gemm_nn<<<dim3(32,2),256,0,stream>>>(x, Wx + (size_t)1*FDIM*CDIM, bx + 1*CDIM, xs1, CDIM, 30, 1);
  gemm_nn<<<dim3(32,2),256,0,stream>>>(x, Wx + (size_t)2*FDIM*CDIM, bx + 2*CDIM, xs2, CDIM, 30, 1);

  // ---- result = [xs1 @ ng1^T , xs2 @ ng2^T]  (4096 x 8192) ----
  gemm_nt<<<dim3(32,32),256,0,stream>>>(xs1, ng1, outp, 8192, 0);
  gemm_nt<<<dim3(32,32),256,0,stream>>>(xs2, ng2, outp, 8192, 4096);

  // ---- second output: h (12288 x 256) ----
  hipMemcpyAsync(outp + (size_t)4096*8192, acc, SZ_H*4, hipMemcpyDeviceToDevice, stream);
}

// Round 4
// 1659.105 us; speedup vs baseline: 1.2543x; 1.1027x over previous
//
#include <hip/hip_runtime.h>
#include <cmath>

#define E_INC   393216
#define NN_     12288
#define MM_     16384
#define FDIM    256
#define CDIM    128
#define PKEYS   128
#define LCAP    6144

__host__ __device__ inline int stBase(int r){ return r<3 ? r*(NN_+1) : 3*(NN_+1) + (r-3)*(MM_+1); }
__host__ __device__ inline int nParts(int r){ return (r<3 ? NN_ : MM_) / PKEYS; }  // 96 or 128

__device__ __forceinline__ float lrelu(float v){ return v >= 0.0f ? v : 0.2f*v; }

struct Ptrs6 { const int* p[6]; };

// ---------------- CSR build: two-level partition (write-locality) ----------------
__global__ __launch_bounds__(256) void coarse_hist(Ptrs6 keys, int* __restrict__ ccnt){
  __shared__ int h[PKEYS];
  int r = blockIdx.y, t = threadIdx.x;
  if (t < PKEYS) h[t] = 0;
  __syncthreads();
  int base = blockIdx.x * 4096;
  const int* ka = keys.p[r];
  for (int j=0;j<16;++j) atomicAdd(&h[ka[base + j*256 + t] >> 7], 1);
  __syncthreads();
  if (t < PKEYS) atomicAdd(&ccnt[r*PKEYS + t], h[t]);
}

__global__ __launch_bounds__(128) void coarse_scan(const int* __restrict__ ccnt,
                                                   int* __restrict__ cstart,
                                                   int* __restrict__ ccur){
  int r = blockIdx.x, t = threadIdx.x;
  int P = nParts(r);
  int c = (t < P) ? ccnt[r*PKEYS + t] : 0;
  __shared__ int sd[128];
  sd[t] = c; __syncthreads();
  for (int ofs=1; ofs<128; ofs<<=1){
    int v = (t>=ofs) ? sd[t-ofs] : 0;
    __syncthreads(); sd[t] += v; __syncthreads();
  }
  int excl = sd[t] - c;
  cstart[r*129 + t] = excl;
  ccur[r*PKEYS + t] = excl;
  if (t == 127) cstart[r*129 + 128] = sd[127];
}

__global__ __launch_bounds__(256) void part_scatter(Ptrs6 keys, int* __restrict__ ccur,
                                                    int* __restrict__ pbuf){
  __shared__ int h[PKEYS];
  __shared__ int cur[PKEYS];
  int r = blockIdx.y, t = threadIdx.x;
  if (t < PKEYS) h[t] = 0;
  __syncthreads();
  int base = blockIdx.x * 4096;
  const int* ka = keys.p[r];
  int myk[16];
  for (int j=0;j<16;++j){
    myk[j] = ka[base + j*256 + t] >> 7;
    atomicAdd(&h[myk[j]], 1);
  }
  __syncthreads();
  if (t < PKEYS) cur[t] = atomicAdd(&ccur[r*PKEYS + t], h[t]);
  __syncthreads();
  int* pb = pbuf + (size_t)r * E_INC;
  for (int j=0;j<16;++j){
    int pos = atomicAdd(&cur[myk[j]], 1);
    pb[pos] = base + j*256 + t;
  }
}

__global__ __launch_bounds__(256) void fine_build(Ptrs6 keys, const int* __restrict__ cstart,
                                                  const int* __restrict__ pbuf,
                                                  int* __restrict__ starts,
                                                  int* __restrict__ lists){
  __shared__ unsigned short kb[LCAP];
  __shared__ int ob[LCAP];
  __shared__ int h[PKEYS], ls[PKEYS], lc[PKEYS];
  int r = blockIdx.y, p = blockIdx.x, t = threadIdx.x;
  int P = nParts(r);
  if (p >= P) return;
  int lo = cstart[r*129 + p], hi = cstart[r*129 + p + 1];
  int len = hi - lo;
  if (t < PKEYS) h[t] = 0;
  __syncthreads();
  const int* ka = keys.p[r];
  const int* pb = pbuf + (size_t)r * E_INC;
  int* lst = lists + (size_t)r * E_INC;
  int kbase = p << 7;
  int sb = stBase(r);
  if (len <= LCAP){
    for (int i=t; i<len; i+=256){
      int e = pb[lo+i];
      int k = ka[e] - kbase;
      kb[i] = (unsigned short)k;
      atomicAdd(&h[k], 1);
    }
    __syncthreads();
    if (t == 0){ int run = 0; for (int k=0;k<PKEYS;++k){ ls[k]=run; lc[k]=run; run+=h[k]; } }
    __syncthreads();
    for (int i=t; i<len; i+=256){
      int pos = atomicAdd(&lc[kb[i]], 1);
      ob[pos] = pb[lo+i];
    }
    __syncthreads();
    for (int i=t; i<len; i+=256) lst[lo+i] = ob[i];
    if (t < PKEYS) starts[sb + kbase + t] = lo + ls[t];
  } else {
    for (int i=t; i<len; i+=256) atomicAdd(&h[ka[pb[lo+i]] - kbase], 1);
    __syncthreads();
    if (t == 0){ int run = 0; for (int k=0;k<PKEYS;++k){ ls[k]=run; lc[k]=run; run+=h[k]; } }
    __syncthreads();
    for (int i=t; i<len; i+=256){
      int e = pb[lo+i];
      int pos = atomicAdd(&lc[ka[e] - kbase], 1);
      lst[lo+pos] = e;
    }
    if (t < PKEYS) starts[sb + kbase + t] = lo + ls[t];
  }
  if (p == P-1 && t == 0) starts[sb + (r<3 ? NN_ : MM_)] = hi;
}

// sort each bucket ascending -> accumulation order == numpy sequential order.
__global__ __launch_bounds__(256) void sortb_kernel(const int* __restrict__ starts,
                                                    int* __restrict__ lists){
  int r = blockIdx.y;
  int nb = (r<3) ? NN_ : MM_;
  int wid = (blockIdx.x*256 + threadIdx.x) >> 6;
  int lane = threadIdx.x & 63;
  if (wid >= nb) return;
  int sb = stBase(r);
  int lo = starts[sb+wid], hi = starts[sb+wid+1];
  int len = hi - lo;
  if (len <= 1) return;
  int* lst = lists + (size_t)r*E_INC;
  if (len <= 64){
    int v = (lane < len) ? lst[lo+lane] : 0x7fffffff;
#pragma unroll
    for (int k = 2; k <= 64; k <<= 1){
#pragma unroll
      for (int j = k>>1; j > 0; j >>= 1){
        int o = __shfl_xor(v, j);
        bool up    = ((lane & k) == 0);
        bool lower = ((lane & j) == 0);
        int mn = min(v,o), mx = max(v,o);
        v = (lower == up) ? mn : mx;
      }
    }
    if (lane < len) lst[lo+lane] = v;
  } else if (lane == 0) {
    for (int i=lo+1; i<hi; ++i){
      int key = lst[i]; int j = i-1;
      while (j>=lo && lst[j]>key){ lst[j+1]=lst[j]; --j; }
      lst[j+1]=key;
    }
  }
}

// ---------------- fp32 GEMMs ----------------
__global__ __launch_bounds__(256)
void gemm_nn(const float* __restrict__ A, const float* __restrict__ W,
             const float* __restrict__ bias, float* __restrict__ C,
             int N, int segShift, int act)
{
  __shared__ alignas(16) float As[16][132];
  __shared__ alignas(16) float Bs[16][68];
  int t = threadIdx.x;
  int bm = blockIdx.x * 128;
  int bn = blockIdx.y * 64;
  int seg = bm >> segShift;
  const float* Wp = W + (size_t)seg * FDIM * N;
  int tx = t & 15, ty = t >> 4;
  int arow = t >> 1, akq = (t & 1) << 3;
  int brow = t >> 4, bcol = (t & 15) << 2;

  float acc[8][4] = {};
  for (int k0 = 0; k0 < FDIM; k0 += 16){
    const float* ap = A + (size_t)(bm+arow)*FDIM + k0 + akq;
    float4 a0 = *(const float4*)(ap);
    float4 a1 = *(const float4*)(ap + 4);
    As[akq+0][arow]=a0.x; As[akq+1][arow]=a0.y; As[akq+2][arow]=a0.z; As[akq+3][arow]=a0.w;
    As[akq+4][arow]=a1.x; As[akq+5][arow]=a1.y; As[akq+6][arow]=a1.z; As[akq+7][arow]=a1.w;
    *(float4*)&Bs[brow][bcol] = *(const float4*)(Wp + (size_t)(k0+brow)*N + bn + bcol);
    __syncthreads();
#pragma unroll
    for (int kk=0; kk<16; ++kk){
      float4 x0 = *(const float4*)&As[kk][ty<<3];
      float4 x1 = *(const float4*)&As[kk][(ty<<3)+4];
      float4 bv = *(const float4*)&Bs[kk][tx<<2];
      float af[8] = {x0.x,x0.y,x0.z,x0.w,x1.x,x1.y,x1.z,x1.w};
      float bf[4] = {bv.x,bv.y,bv.z,bv.w};
#pragma unroll
      for (int i=0;i<8;++i)
#pragma unroll
        for (int j=0;j<4;++j) acc[i][j] = fmaf(af[i], bf[j], acc[i][j]);
    }
    __syncthreads();
  }
  int c0 = bn + (tx<<2);
  float4 bb = make_float4(0.f,0.f,0.f,0.f);
  if (bias) bb = *(const float4*)(bias + (size_t)seg*N + c0);
#pragma unroll
  for (int i=0;i<8;++i){
    float4 o = make_float4(acc[i][0],acc[i][1],acc[i][2],acc[i][3]);
    if (bias){ o.x+=bb.x; o.y+=bb.y; o.z+=bb.z; o.w+=bb.w; }
    if (act){ o.x=lrelu(o.x); o.y=lrelu(o.y); o.z=lrelu(o.z); o.w=lrelu(o.w); }
    *(float4*)(C + (size_t)(bm+(ty<<3)+i)*N + c0) = o;
  }
}

__global__ __launch_bounds__(256)
void gemm_nt(const float* __restrict__ A, const float* __restrict__ B,
             float* __restrict__ C, int ldc, int colOff)
{
  __shared__ alignas(16) float As[16][132];
  __shared__ alignas(16) float Bs[16][132];
  int t = threadIdx.x;
  int bm = blockIdx.x * 128;
  int bn = blockIdx.y * 128;
  int tx = t & 15, ty = t >> 4;
  int arow = t >> 1, akq = (t & 1) << 3;

  float acc[8][8] = {};
  for (int k0 = 0; k0 < CDIM; k0 += 16){
    const float* ap = A + (size_t)(bm+arow)*CDIM + k0 + akq;
    float4 a0 = *(const float4*)(ap);
    float4 a1 = *(const float4*)(ap + 4);
    As[akq+0][arow]=a0.x; As[akq+1][arow]=a0.y; As[akq+2][arow]=a0.z; As[akq+3][arow]=a0.w;
    As[akq+4][arow]=a1.x; As[akq+5][arow]=a1.y; As[akq+6][arow]=a1.z; As[akq+7][arow]=a1.w;
    const float* bp = B + (size_t)(bn+arow)*CDIM + k0 + akq;
    float4 b0 = *(const float4*)(bp);
    float4 b1 = *(const float4*)(bp + 4);
    Bs[akq+0][arow]=b0.x; Bs[akq+1][arow]=b0.y; Bs[akq+2][arow]=b0.z; Bs[akq+3][arow]=b0.w;
    Bs[akq+4][arow]=b1.x; Bs[akq+5][arow]=b1.y; Bs[akq+6][arow]=b1.z; Bs[akq+7][arow]=b1.w;
    __syncthreads();
#pragma unroll
    for (int kk=0; kk<16; ++kk){
      float4 x0 = *(const float4*)&As[kk][ty<<3];
      float4 x1 = *(const float4*)&As[kk][(ty<<3)+4];
      float4 y0 = *(const float4*)&Bs[kk][tx<<3];
      float4 y1 = *(const float4*)&Bs[kk][(tx<<3)+4];
      float af[8] = {x0.x,x0.y,x0.z,x0.w,x1.x,x1.y,x1.z,x1.w};
      float bf[8] = {y0.x,y0.y,y0.z,y0.w,y1.x,y1.y,y1.z,y1.w};
#pragma unroll
      for (int i=0;i<8;++i)
#pragma unroll
        for (int j=0;j<8;++j) acc[i][j] = fmaf(af[i], bf[j], acc[i][j]);
    }
    __syncthreads();
  }
  int c0 = colOff + bn + (tx<<3);
#pragma unroll
  for (int i=0;i<8;++i){
    float* cp = C + (size_t)(bm+(ty<<3)+i)*ldc + c0;
    *(float4*)(cp)   = make_float4(acc[i][0],acc[i][1],acc[i][2],acc[i][3]);
    *(float4*)(cp+4) = make_float4(acc[i][4],acc[i][5],acc[i][6],acc[i][7]);
  }
}

// ---------------- attention scalars (hoisted + fused) ----------------
// vv[cfg][r] = dot(W[cfg] row r, attB[cfg]); cfg = layer*3+branch, 6 cfgs x 256 rows
__global__ __launch_bounds__(256)
void vv_all(const float* __restrict__ Wh1, const float* __restrict__ Wh2,
            const float* __restrict__ att1, const float* __restrict__ att2,
            float* __restrict__ vvb)
{
  int g = blockIdx.x*256 + threadIdx.x;
  int w = g >> 6, lane = g & 63;
  if (w >= 6*FDIM) return;
  int cfg = w >> 8, rr = w & 255;
  int l = cfg / 3, k = cfg % 3;
  const float* r = (l ? Wh2 : Wh1) + (size_t)k*FDIM*FDIM + (size_t)rr*FDIM;
  const float* vec = (l ? att2 : att1) + (size_t)k*2*FDIM + FDIM;
  double s = 0.0;
#pragma unroll
  for (int c=lane; c<FDIM; c+=64) s = fma((double)r[c], (double)vec[c], s);
  for (int ofs=32; ofs; ofs>>=1) s += __shfl_down(s, ofs);
  if (lane==0) vvb[cfg*FDIM + rr] = (float)s;
}

// s2all[cfg][row] = dot(hattr row, vv[cfg]) -- one pass over hattr for all 6 cfgs
__global__ __launch_bounds__(256)
void s2_all(const float* __restrict__ hattr, const float* __restrict__ vvb,
            float* __restrict__ s2all)
{
  __shared__ float vs[6*FDIM];
  int t = threadIdx.x;
  for (int i=t; i<6*FDIM; i+=256) vs[i] = vvb[i];
  __syncthreads();
  int g = blockIdx.x*256 + t;
  int w = g >> 6, lane = g & 63;
  if (w >= MM_) return;
  const float* r = hattr + (size_t)w*FDIM;
  double s[6] = {0,0,0,0,0,0};
#pragma unroll
  for (int c=lane; c<FDIM; c+=64){
    double xv = (double)r[c];
#pragma unroll
    for (int q=0;q<6;++q) s[q] = fma(xv, (double)vs[q*FDIM + c], s[q]);
  }
#pragma unroll
  for (int q=0;q<6;++q){
    double v = s[q];
    for (int ofs=32; ofs; ofs>>=1) v += __shfl_down(v, ofs);
    if (lane==0) s2all[(size_t)q*MM_ + w] = (float)v;
  }
}

// fused: s1 (fp64 in-wave) + amax + asum + dinv + alpha writes, one wave per node
__global__ __launch_bounds__(256)
void node_alpha(const int* __restrict__ starts, const int* __restrict__ list,
                const int* __restrict__ ei, const float* __restrict__ xl,
                const float* __restrict__ attA, const float* __restrict__ s2,
                const float* __restrict__ hw,
                float* __restrict__ dinv, float* __restrict__ alpha)
{
  int g = blockIdx.x*256 + threadIdx.x;
  int w = g >> 6, lane = g & 63;
  if (w >= NN_) return;
  // s1 = dot(xl row w, attA), fp64, identical order to old rowdot
  const float* r = xl + (size_t)w*FDIM;
  double s = 0.0;
#pragma unroll
  for (int c=lane; c<FDIM; c+=64) s = fma((double)r[c], (double)attA[c], s);
  for (int ofs=32; ofs; ofs>>=1) s += __shfl_down(s, ofs);
  s = __shfl(s, 0);
  float s1n = (float)s;

  int lo = starts[w], hi = starts[w+1];
  float mx = -INFINITY;
  for (int i=lo+lane; i<hi; i+=64){
    int e = list[i];
    mx = fmaxf(mx, lrelu(s1n + s2[ei[e]]));
  }
  for (int ofs=32; ofs; ofs>>=1) mx = fmaxf(mx, __shfl_xor(mx, ofs));
  if (lo == hi) mx = 0.0f;
  double se = 0.0, sd = 0.0;
  for (int i=lo+lane; i<hi; i+=64){
    int e = list[i]; int m = ei[e];
    float a = lrelu(s1n + s2[m]);
    se += (double)expf(a - mx);
    sd += (double)hw[m];
  }
  for (int ofs=32; ofs; ofs>>=1){ se += __shfl_xor(se, ofs); sd += __shfl_xor(sd, ofs); }
  float sumf = (float)se;
  if (lane==0){
    float D = (float)sd;
    dinv[w] = (D > 0.0f) ? 1.0f/D : 0.0f;
  }
  for (int i=lo+lane; i<hi; i+=64){
    int e = list[i];
    float a = lrelu(s1n + s2[ei[e]]);
    alpha[e] = expf(a - mx) / sumf;
  }
}

// ---------------- propagation (gather via CSR, np-order exact, 8-deep MLP) ----------------
__global__ __launch_bounds__(256)
void m_kernel(const int* __restrict__ estarts, const int* __restrict__ elist,
              const int* __restrict__ ni, const float* __restrict__ alpha,
              const float* __restrict__ xl, float* __restrict__ m)
{
  int g = blockIdx.x*256 + threadIdx.x;
  int w = g >> 6, lane = g & 63;
  if (w >= MM_) return;
  int lo = estarts[w], hi = estarts[w+1];
  float binv = (hi > lo) ? 1.0f/(float)(hi-lo) : 0.0f;
  float ax=0.f, ay=0.f, az=0.f, aw=0.f;
  int col = lane << 2;
  int i = lo;
  while (i < hi){
    int nc = hi - i; if (nc > 8) nc = 8;
    float4 v[8]; float c[8];
#pragma unroll
    for (int j=0;j<8;++j) if (j < nc){
      int e = elist[i+j];
      c[j] = __fmul_rn(binv, alpha[e]);
      v[j] = *(const float4*)(xl + (size_t)ni[e]*FDIM + col);
    }
#pragma unroll
    for (int j=0;j<8;++j) if (j < nc){
      ax = __fadd_rn(ax, __fmul_rn(c[j], v[j].x));
      ay = __fadd_rn(ay, __fmul_rn(c[j], v[j].y));
      az = __fadd_rn(az, __fmul_rn(c[j], v[j].z));
      aw = __fadd_rn(aw, __fmul_rn(c[j], v[j].w));
    }
    i += nc;
  }
  *(float4*)(m + (size_t)w*FDIM + col) = make_float4(ax,ay,az,aw);
}

__global__ __launch_bounds__(256)
void out_kernel(const int* __restrict__ nstarts, const int* __restrict__ nlist,
                const int* __restrict__ ei, const float* __restrict__ alpha,
                const float* __restrict__ dinv, const float* __restrict__ m,
                const float* __restrict__ bias, float* __restrict__ accb,
                float* __restrict__ mirror, int first, int finalAct)
{
  int g = blockIdx.x*256 + threadIdx.x;
  int w = g >> 6, lane = g & 63;
  if (w >= NN_) return;
  int lo = nstarts[w], hi = nstarts[w+1];
  float dv = dinv[w];
  float ax=0.f, ay=0.f, az=0.f, aw=0.f;
  int col = lane << 2;
  int i = lo;
  while (i < hi){
    int nc = hi - i; if (nc > 8) nc = 8;
    float4 v[8]; float c[8];
#pragma unroll
    for (int j=0;j<8;++j) if (j < nc){
      int e = nlist[i+j];
      c[j] = __fmul_rn(dv, alpha[e]);
      v[j] = *(const float4*)(m + (size_t)ei[e]*FDIM + col);
    }
#pragma unroll
    for (int j=0;j<8;++j) if (j < nc){
      ax = __fadd_rn(ax, __fmul_rn(c[j], v[j].x));
      ay = __fadd_rn(ay, __fmul_rn(c[j], v[j].y));
      az = __fadd_rn(az, __fmul_rn(c[j], v[j].z));
      aw = __fadd_rn(aw, __fmul_rn(c[j], v[j].w));
    }
    i += nc;
  }
  const float4 b4 = *(const float4*)(bias + col);
  ax = __fadd_rn(ax, b4.x); ay = __fadd_rn(ay, b4.y);
  az = __fadd_rn(az, b4.z); aw = __fadd_rn(aw, b4.w);
  float* p = accb + (size_t)w*FDIM + col;
  if (!first){
    float4 pr = *(const float4*)p;
    ax = __fadd_rn(pr.x, ax); ay = __fadd_rn(pr.y, ay);
    az = __fadd_rn(pr.z, az); aw = __fadd_rn(pr.w, aw);
  }
  if (finalAct){ ax=lrelu(ax); ay=lrelu(ay); az=lrelu(az); aw=lrelu(aw); }
  float4 o = make_float4(ax,ay,az,aw);
  *(float4*)p = o;
  if (mirror) *(float4*)(mirror + (size_t)w*FDIM + col) = o;
}

// ---------------- host orchestration ----------------
extern "C" void kernel_launch(void* const* d_in, const int* in_sizes, int n_in,
                              void* d_out, int out_size, void* d_ws, size_t ws_size,
                              hipStream_t stream)
{
  (void)in_sizes; (void)n_in; (void)out_size; (void)ws_size;
  const float* g     = (const float*)d_in[0];
  const float* x     = (const float*)d_in[1];
  const float* hw    = (const float*)d_in[2];
  const float* hattr = (const float*)d_in[3];
  const int* ni[3]   = {(const int*)d_in[4], (const int*)d_in[6], (const int*)d_in[8]};
  const int* ei[3]   = {(const int*)d_in[5], (const int*)d_in[7], (const int*)d_in[9]};
  const float* W0  = (const float*)d_in[10];
  const float* b0  = (const float*)d_in[11];
  const float* Wh1 = (const float*)d_in[12];
  const float* att1= (const float*)d_in[13];
  const float* bc1 = (const float*)d_in[14];
  const float* W1  = (const float*)d_in[15];
  const float* b1  = (const float*)d_in[16];
  const float* Wh2 = (const float*)d_in[17];
  const float* att2= (const float*)d_in[18];
  const float* bc2 = (const float*)d_in[19];
  const float* Wg  = (const float*)d_in[20];
  const float* bg  = (const float*)d_in[21];
  const float* Wx  = (const float*)d_in[22];
  const float* bx  = (const float*)d_in[23];
  float* outp = (float*)d_out;

  char* base = (char*)d_ws;
  size_t off = 0;
  auto alloc = [&](size_t bytes)->void*{
    void* p = base + off;
    off = (off + bytes + 255) & ~(size_t)255;
    return p;
  };
  const size_t SZ_H = (size_t)NN_*FDIM;
  float* hA    = (float*)alloc(SZ_H*4);
  float* xl    = (float*)alloc(SZ_H*4);
  float* acc   = (float*)alloc(SZ_H*4);
  float* mbuf  = (float*)alloc((size_t)MM_*FDIM*4);   // aliased as pbuf during CSR build
  float* alphab= (float*)alloc((size_t)E_INC*4);
  float* vvb   = (float*)alloc((size_t)6*FDIM*4);
  float* s2all = (float*)alloc((size_t)6*MM_*4);
  float* dinvb = (float*)alloc(NN_*4);
  float* ngbuf = (float*)alloc((size_t)8192*CDIM*4);
  float* xs1   = (float*)alloc((size_t)4096*CDIM*4);
  float* xs2   = (float*)alloc((size_t)4096*CDIM*4);
  int*   ccnt  = (int*)alloc((size_t)6*PKEYS*4);
  int*   ccur  = (int*)alloc((size_t)6*PKEYS*4);
  int*   cstart= (int*)alloc((size_t)6*129*4);
  int*   stb   = (int*)alloc((size_t)(3*(NN_+1)+3*(MM_+1))*4);
  int*   lists = (int*)alloc((size_t)6*E_INC*4);
  int*   pbuf  = (int*)mbuf;

  // ---- CSR build (shared by both hyper layers) ----
  hipMemsetAsync(ccnt, 0, (size_t)6*PKEYS*4, stream);
  Ptrs6 ip{{ni[0],ni[1],ni[2],ei[0],ei[1],ei[2]}};
  coarse_hist <<<dim3(96,6),256,0,stream>>>(ip, ccnt);
  coarse_scan <<<6,128,0,stream>>>(ccnt, cstart, ccur);
  part_scatter<<<dim3(96,6),256,0,stream>>>(ip, ccur, pbuf);
  fine_build  <<<dim3(128,6),256,0,stream>>>(ip, cstart, pbuf, stb, lists);
  sortb_kernel<<<dim3(4096,6),256,0,stream>>>(stb, lists);

  // ---- h-independent attention scalars: all 6 (layer,branch) configs ----
  vv_all<<<384,256,0,stream>>>(Wh1, Wh2, att1, att2, vvb);
  s2_all<<<4096,256,0,stream>>>(hattr, vvb, s2all);

  // ---- layer0 ----
  gemm_nn<<<dim3(96,4),256,0,stream>>>(g, W0, b0, hA, FDIM, 12, 1);

  auto hyper = [&](int layer, const float* hin, const float* Whs, const float* atts,
                   const float* bcs, float* mirror){
    for (int k=0;k<3;++k){
      const float* Wk   = Whs + (size_t)k*FDIM*FDIM;
      const float* attA = atts + (size_t)k*2*FDIM;
      const float* s2   = s2all + (size_t)(layer*3+k)*MM_;
      const int* nst = stb + stBase(k);
      const int* nls = lists + (size_t)k*E_INC;
      const int* est = stb + stBase(3+k);
      const int* els = lists + (size_t)(3+k)*E_INC;
      gemm_nn   <<<dim3(96,4),256,0,stream>>>(hin, Wk, nullptr, xl, FDIM, 30, 0);
      node_alpha<<<3072,256,0,stream>>>(nst, nls, ei[k], xl, attA, s2, hw, dinvb, alphab);
      m_kernel  <<<4096,256,0,stream>>>(est, els, ni[k], alphab, xl, mbuf);
      out_kernel<<<3072,256,0,stream>>>(nst, nls, ei[k], alphab, dinvb, mbuf,
                                        bcs + (size_t)k*FDIM, acc,
                                        (k==2) ? mirror : nullptr, k==0, k==2);
    }
  };

  hyper(0, hA, Wh1, att1, bc1, nullptr);
  gemm_nn<<<dim3(96,4),256,0,stream>>>(acc, W1, b1, hA, FDIM, 12, 1);
  hyper(1, hA, Wh2, att2, bc2, outp + (size_t)4096*8192);  // mirrors final h to output

  // ---- projections: ng1|ng2 in one segmented launch; xs1,xs2 ----
  gemm_nn<<<dim3(64,2),256,0,stream>>>(acc + (size_t)4096*FDIM, Wg + (size_t)FDIM*CDIM,
                                       bg + CDIM, ngbuf, CDIM, 12, 1);
  gemm_nn<<<dim3(32,2),256,0,stream>>>(x, Wx + (size_t)1*FDIM*CDIM, bx + 1*CDIM, xs1, CDIM, 30, 1);
  gemm_nn<<<dim3(32,2),256,0,stream>>>(x, Wx + (size_t)2*FDIM*CDIM, bx + 2*CDIM, xs2, CDIM, 30, 1);

  // ---- result = [xs1 @ ng1^T , xs2 @ ng2^T]  (4096 x 8192) ----
  gemm_nt<<<dim3(32,32),256,0,stream>>>(xs1, ngbuf, outp, 8192, 0);
  gemm_nt<<<dim3(32,32),256,0,stream>>>(xs2, ngbuf + (size_t)4096*CDIM, outp, 8192, 4096);
}